// Round 3
// baseline (366.830 us; speedup 1.0000x reference)
//
#include <hip/hip_runtime.h>
#include <stdint.h>

#define N_NODES 100000
#define N_EDGES 3200000
#define DIM 128
#define NPAD 100032   // 1563 * 64
#define NBINS 391     // ceil(100000 / 256) -- 256 nodes per bin
#define BCAP 10240    // bin capacity; mean 8192
#define EPB 4096      // edges per bin_kernel block (16/thread)

typedef short short8 __attribute__((ext_vector_type(8)));
typedef float f32x4 __attribute__((ext_vector_type(4)));
typedef float f32x2 __attribute__((ext_vector_type(2)));

__device__ __forceinline__ short f2bf(float x) {
    uint32_t u = __builtin_bit_cast(uint32_t, x);
    u += 0x7fffu + ((u >> 16) & 1u);   // round-to-nearest-even
    return (short)(u >> 16);
}
__device__ __forceinline__ float bflo(uint32_t p) {
    return __builtin_bit_cast(float, p << 16);
}
__device__ __forceinline__ float bfhi(uint32_t p) {
    return __builtin_bit_cast(float, p & 0xffff0000u);
}
__device__ __forceinline__ uint32_t pack2(float x, float y) {
    return (uint32_t)(uint16_t)f2bf(x) | ((uint32_t)(uint16_t)f2bf(y) << 16);
}
__device__ __forceinline__ f32x2 up2(uint32_t p) {
    return (f32x2){ bflo(p), bfhi(p) };
}

// ---- K1: fused prep: feat->bf16 cast, W transpose, bincnt zero ----------
__global__ __launch_bounds__(256) void prep_kernel(const float* __restrict__ feat,
                                                   uint32_t* __restrict__ featbf,
                                                   const float* __restrict__ w1,
                                                   const float* __restrict__ w2,
                                                   short* __restrict__ w1t,
                                                   short* __restrict__ w2t,
                                                   int* __restrict__ bincnt) {
    int b = blockIdx.x, t = threadIdx.x;
    if (b < 12500) {                       // cast: 3.2M float4s
        int i = b * 256 + t;
        float4 f = ((const float4*)feat)[i];
        featbf[2 * i]     = pack2(f.x, f.y);
        featbf[2 * i + 1] = pack2(f.z, f.w);
    } else if (b < 12564) {                // weight transpose: 16384 elems
        int i = (b - 12500) * 256 + t;
        int k = i >> 7, n = i & 127;
        w1t[n * DIM + k] = f2bf(w1[i]);
        w2t[n * DIM + k] = f2bf(w2[i]);
    } else {                               // zero bincnt (512 ints over 2 blocks)
        int i = (b - 12564) * 256 + t;
        bincnt[i] = 0;
    }
}

// ---- K3a: bin edges by dst>>8, LDS counting-sort, coalesced write-out ---
__global__ __launch_bounds__(256) void bin_kernel(const int* __restrict__ src,
                                                  const int* __restrict__ dst,
                                                  int* __restrict__ bincnt,
                                                  uint32_t* __restrict__ binpair) {
    __shared__ int hist[512];
    __shared__ int scanv[512];
    __shared__ int scan256[256];
    __shared__ int gbase[NBINS];
    __shared__ int cursor[NBINS];
    __shared__ uint32_t sorted[EPB];
    __shared__ int saddr[EPB];
    int t = threadIdx.x;
    for (int i = t; i < 512; i += 256) hist[i] = 0;
    __syncthreads();
    int e0 = blockIdx.x * EPB;
    int nn = min(EPB, N_EDGES - e0);
    int d[16];
#pragma unroll
    for (int i = 0; i < 16; i++) {
        int idx = i * 256 + t;
        d[i] = (idx < nn) ? dst[e0 + idx] : -1;
        if (d[i] >= 0) atomicAdd(&hist[d[i] >> 8], 1);
    }
    __syncthreads();
    int h0 = hist[2 * t], h1 = hist[2 * t + 1];
    scan256[t] = h0 + h1;
    __syncthreads();
    for (int dd = 1; dd < 256; dd <<= 1) {
        int v = (t >= dd) ? scan256[t - dd] : 0;
        __syncthreads();
        scan256[t] += v;
        __syncthreads();
    }
    int pairExcl = scan256[t] - (h0 + h1);
    scanv[2 * t] = pairExcl;
    scanv[2 * t + 1] = pairExcl + h0;
    for (int b = t; b < NBINS; b += 256) {
        int h = hist[b];
        gbase[b] = h ? atomicAdd(&bincnt[b], h) : 0;
        cursor[b] = 0;
    }
    __syncthreads();
#pragma unroll
    for (int i = 0; i < 16; i++) {
        if (d[i] >= 0) {
            int b = d[i] >> 8;
            int slot = atomicAdd(&cursor[b], 1);
            int p = scanv[b] + slot;
            int g = gbase[b] + slot;
            int e = e0 + i * 256 + t;
            sorted[p] = (uint32_t)src[e] | ((uint32_t)(d[i] & 255) << 24);
            saddr[p] = (g < BCAP) ? (b * BCAP + g) : -1;
        }
    }
    __syncthreads();
    for (int i = t; i < nn; i += 256) {
        int a = saddr[i];
        if (a >= 0) binpair[a] = sorted[i];
    }
}

// ---- K3b: per-bin counting sort -> CSR (1024 thr, LDS-staged coalesced) -
__global__ __launch_bounds__(1024) void csr_kernel(const int* __restrict__ bincnt,
                                                   const uint32_t* __restrict__ binpair,
                                                   int* __restrict__ rowptr,
                                                   int* __restrict__ csr) {
    __shared__ int hist[256];
    __shared__ int cursor[256];
    __shared__ int sc[256];
    __shared__ int red[256];
    __shared__ int binbase_s;
    __shared__ int sorted_s[BCAP];
    int b = blockIdx.x;
    int t = threadIdx.x;
    if (t < 256) {
        int partial = 0;
        for (int j = t; j < b; j += 256) partial += min(bincnt[j], BCAP);
        red[t] = partial;
        hist[t] = 0;
    }
    __syncthreads();
    for (int dd = 128; dd > 0; dd >>= 1) {
        if (t < dd) red[t] += red[t + dd];
        __syncthreads();
    }
    if (t == 0) binbase_s = red[0];
    __syncthreads();
    int binbase = binbase_s;
    int cntb = min(bincnt[b], BCAP);
    const uint32_t* pairs = binpair + (size_t)b * BCAP;
    for (int i = t; i < cntb; i += 1024)
        atomicAdd(&hist[pairs[i] >> 24], 1);
    __syncthreads();
    int val = 0;
    if (t < 256) { val = hist[t]; sc[t] = val; }
    __syncthreads();
    for (int dd = 1; dd < 256; dd <<= 1) {
        int addv = (t < 256 && t >= dd) ? sc[t - dd] : 0;
        __syncthreads();
        if (t < 256) sc[t] += addv;
        __syncthreads();
    }
    if (t < 256) {
        int excl = sc[t] - val;
        rowptr[(b << 8) + t] = binbase + excl;
        cursor[t] = excl;
    }
    __syncthreads();
    for (int i = t; i < cntb; i += 1024) {
        uint32_t p = pairs[i];
        int s2 = atomicAdd(&cursor[p >> 24], 1);
        sorted_s[s2] = (int)(p & 0x00FFFFFFu);
    }
    __syncthreads();
    for (int i = t; i < cntb; i += 1024)
        csr[binbase + i] = sorted_s[i];
}

// load helper: broadcast index from lane `sl`, load that row's 16B column
#define LDQ(qv, sl) do { int _i = __shfl(u, (sl)); \
    qv = *(const uint4*)&featbf[_i * 64 + col * 4]; } while (0)

#define ACCN(q, A01, A23, A45, A67) do { \
    A01 += up2((q).x); A23 += up2((q).y); A45 += up2((q).z); A67 += up2((q).w); } while (0)

// ---- K4: 2 nodes per wave, interleaved bursts (16 loads in flight) ------
__global__ __launch_bounds__(256) void gather_kernel(const uint32_t* __restrict__ featbf,
                                                     const int* __restrict__ rowptr,
                                                     const int* __restrict__ csr,
                                                     const float* __restrict__ eps,
                                                     uint32_t* __restrict__ hbf) {
    int gw = blockIdx.x * 4 + (threadIdx.x >> 6);   // wave id
    int nA = gw * 2, nB = nA + 1;
    int lane = threadIdx.x & 63;
    int quarter = lane >> 4;
    int col = lane & 15;
    if (nA >= N_NODES) {                 // both rows are padding
        if (nA < NPAD) {
            hbf[nA * 64 + lane] = 0;
            hbf[nB * 64 + lane] = 0;
        }
        return;
    }
    // nA even and < 100000 (even) => nB < N_NODES always
    float e1 = 1.0f + eps[0];
    uint4 sfA = *(const uint4*)&featbf[nA * 64 + col * 4];
    uint4 sfB = *(const uint4*)&featbf[nB * 64 + col * 4];
    int sA = rowptr[nA];
    int eA = rowptr[nA + 1];
    int eB = rowptr[nA + 2];
    int baseA = sA, baseB = eA;          // rowptr[nB] == eA
    int endA = eA, endB = eB;

    f32x2 A01 = (f32x2){0.f,0.f}, A23 = (f32x2){0.f,0.f};
    f32x2 A45 = (f32x2){0.f,0.f}, A67 = (f32x2){0.f,0.f};
    f32x2 B01 = (f32x2){0.f,0.f}, B23 = (f32x2){0.f,0.f};
    f32x2 B45 = (f32x2){0.f,0.f}, B67 = (f32x2){0.f,0.f};

    int p0 = quarter,      p1 = 4 + quarter;
    int p2 = 8 + quarter,  p3 = 12 + quarter;
    int p4 = 16 + quarter, p5 = 20 + quarter;
    int p6 = 24 + quarter, p7 = 28 + quarter;
    int l32 = lane & 31;

    while (baseA < endA || baseB < endB) {
        int rA = endA - baseA; int mA = rA > 32 ? 32 : (rA > 0 ? rA : 0);
        int rB = endB - baseB; int mB = rB > 32 ? 32 : (rB > 0 ? rB : 0);
        // combined csr fetch: lanes 0..31 -> A slots, lanes 32..63 -> B slots
        int cbase = (lane < 32) ? baseA : baseB;
        int cm    = (lane < 32) ? mA : mB;
        int u = (l32 < cm) ? csr[cbase + l32] : 0;

        uint4 qa0, qa1, qa2, qa3, qa4, qa5, qa6, qa7;
        uint4 qb0, qb1, qb2, qb3, qb4, qb5, qb6, qb7;
        int mmA = mA - 1, mmB = mB - 1;
        // ---- issue phase A (graded 8/4/2/1) ----
        if (mA > 16) {
            LDQ(qa0, p0); LDQ(qa1, p1); LDQ(qa2, p2); LDQ(qa3, p3);
            LDQ(qa4, min(p4, mmA)); LDQ(qa5, min(p5, mmA));
            LDQ(qa6, min(p6, mmA)); LDQ(qa7, min(p7, mmA));
        } else if (mA > 8) {
            LDQ(qa0, p0); LDQ(qa1, p1);
            LDQ(qa2, min(p2, mmA)); LDQ(qa3, min(p3, mmA));
        } else if (mA > 4) {
            LDQ(qa0, p0); LDQ(qa1, min(p1, mmA));
        } else if (mA > 0) {
            LDQ(qa0, min(p0, mmA));
        }
        // ---- issue phase B ----
        if (mB > 16) {
            LDQ(qb0, 32 + p0); LDQ(qb1, 32 + p1); LDQ(qb2, 32 + p2); LDQ(qb3, 32 + p3);
            LDQ(qb4, 32 + min(p4, mmB)); LDQ(qb5, 32 + min(p5, mmB));
            LDQ(qb6, 32 + min(p6, mmB)); LDQ(qb7, 32 + min(p7, mmB));
        } else if (mB > 8) {
            LDQ(qb0, 32 + p0); LDQ(qb1, 32 + p1);
            LDQ(qb2, 32 + min(p2, mmB)); LDQ(qb3, 32 + min(p3, mmB));
        } else if (mB > 4) {
            LDQ(qb0, 32 + p0); LDQ(qb1, 32 + min(p1, mmB));
        } else if (mB > 0) {
            LDQ(qb0, 32 + min(p0, mmB));
        }
        // ---- consume phase A ----
        if (mA > 16) {
            ACCN(qa0, A01, A23, A45, A67); ACCN(qa1, A01, A23, A45, A67);
            ACCN(qa2, A01, A23, A45, A67); ACCN(qa3, A01, A23, A45, A67);
            if (p4 < mA) ACCN(qa4, A01, A23, A45, A67);
            if (p5 < mA) ACCN(qa5, A01, A23, A45, A67);
            if (p6 < mA) ACCN(qa6, A01, A23, A45, A67);
            if (p7 < mA) ACCN(qa7, A01, A23, A45, A67);
        } else if (mA > 8) {
            ACCN(qa0, A01, A23, A45, A67); ACCN(qa1, A01, A23, A45, A67);
            if (p2 < mA) ACCN(qa2, A01, A23, A45, A67);
            if (p3 < mA) ACCN(qa3, A01, A23, A45, A67);
        } else if (mA > 4) {
            ACCN(qa0, A01, A23, A45, A67);
            if (p1 < mA) ACCN(qa1, A01, A23, A45, A67);
        } else if (mA > 0) {
            if (p0 < mA) ACCN(qa0, A01, A23, A45, A67);
        }
        // ---- consume phase B ----
        if (mB > 16) {
            ACCN(qb0, B01, B23, B45, B67); ACCN(qb1, B01, B23, B45, B67);
            ACCN(qb2, B01, B23, B45, B67); ACCN(qb3, B01, B23, B45, B67);
            if (p4 < mB) ACCN(qb4, B01, B23, B45, B67);
            if (p5 < mB) ACCN(qb5, B01, B23, B45, B67);
            if (p6 < mB) ACCN(qb6, B01, B23, B45, B67);
            if (p7 < mB) ACCN(qb7, B01, B23, B45, B67);
        } else if (mB > 8) {
            ACCN(qb0, B01, B23, B45, B67); ACCN(qb1, B01, B23, B45, B67);
            if (p2 < mB) ACCN(qb2, B01, B23, B45, B67);
            if (p3 < mB) ACCN(qb3, B01, B23, B45, B67);
        } else if (mB > 4) {
            ACCN(qb0, B01, B23, B45, B67);
            if (p1 < mB) ACCN(qb1, B01, B23, B45, B67);
        } else if (mB > 0) {
            if (p0 < mB) ACCN(qb0, B01, B23, B45, B67);
        }
        baseA += mA; baseB += mB;
    }

    // cross-quarter reductions (A and B chains interleave, independent)
    float a0 = A01.x, a1 = A01.y, a2 = A23.x, a3 = A23.y;
    float a4 = A45.x, a5 = A45.y, a6 = A67.x, a7 = A67.y;
    float b0 = B01.x, b1 = B01.y, b2 = B23.x, b3 = B23.y;
    float b4 = B45.x, b5 = B45.y, b6 = B67.x, b7 = B67.y;
    a0 += __shfl_xor(a0, 16); b0 += __shfl_xor(b0, 16);
    a1 += __shfl_xor(a1, 16); b1 += __shfl_xor(b1, 16);
    a2 += __shfl_xor(a2, 16); b2 += __shfl_xor(b2, 16);
    a3 += __shfl_xor(a3, 16); b3 += __shfl_xor(b3, 16);
    a4 += __shfl_xor(a4, 16); b4 += __shfl_xor(b4, 16);
    a5 += __shfl_xor(a5, 16); b5 += __shfl_xor(b5, 16);
    a6 += __shfl_xor(a6, 16); b6 += __shfl_xor(b6, 16);
    a7 += __shfl_xor(a7, 16); b7 += __shfl_xor(b7, 16);
    a0 += __shfl_xor(a0, 32); b0 += __shfl_xor(b0, 32);
    a1 += __shfl_xor(a1, 32); b1 += __shfl_xor(b1, 32);
    a2 += __shfl_xor(a2, 32); b2 += __shfl_xor(b2, 32);
    a3 += __shfl_xor(a3, 32); b3 += __shfl_xor(b3, 32);
    a4 += __shfl_xor(a4, 32); b4 += __shfl_xor(b4, 32);
    a5 += __shfl_xor(a5, 32); b5 += __shfl_xor(b5, 32);
    a6 += __shfl_xor(a6, 32); b6 += __shfl_xor(b6, 32);
    a7 += __shfl_xor(a7, 32); b7 += __shfl_xor(b7, 32);
    if (quarter == 0) {        // 16 lanes store node A
        a0 += e1 * bflo(sfA.x); a1 += e1 * bfhi(sfA.x);
        a2 += e1 * bflo(sfA.y); a3 += e1 * bfhi(sfA.y);
        a4 += e1 * bflo(sfA.z); a5 += e1 * bfhi(sfA.z);
        a6 += e1 * bflo(sfA.w); a7 += e1 * bfhi(sfA.w);
        uint4 w;
        w.x = pack2(a0, a1); w.y = pack2(a2, a3);
        w.z = pack2(a4, a5); w.w = pack2(a6, a7);
        *(uint4*)&hbf[nA * 64 + col * 4] = w;
    } else if (quarter == 1) { // 16 lanes store node B in parallel
        b0 += e1 * bflo(sfB.x); b1 += e1 * bfhi(sfB.x);
        b2 += e1 * bflo(sfB.y); b3 += e1 * bfhi(sfB.y);
        b4 += e1 * bflo(sfB.z); b5 += e1 * bfhi(sfB.z);
        b6 += e1 * bflo(sfB.w); b7 += e1 * bfhi(sfB.w);
        uint4 w;
        w.x = pack2(b0, b1); w.y = pack2(b2, b3);
        w.z = pack2(b4, b5); w.w = pack2(b6, b7);
        *(uint4*)&hbf[nB * 64 + col * 4] = w;
    }
}

// ---- K5: fused 2-layer MLP via bf16 MFMA 16x16x32 -----------------------
__global__ __launch_bounds__(256) void mlp_kernel(const short* __restrict__ hbf,
                                                  const short* __restrict__ w1t,
                                                  const short* __restrict__ w2t,
                                                  const float* __restrict__ b1,
                                                  const float* __restrict__ b2,
                                                  float* __restrict__ out) {
    __shared__ __align__(16) short h1s[4][16 * 136];
    const int wave = threadIdx.x >> 6;
    const int lane = threadIdx.x & 63;
    const int l15 = lane & 15;
    const int quad = lane >> 4;

    float b1v[8], b2v[8];
#pragma unroll
    for (int n = 0; n < 8; n++) {
        b1v[n] = b1[n * 16 + l15];
        b2v[n] = b2[n * 16 + l15];
    }

    const int ntiles = NPAD / 64;
    for (int tile = blockIdx.x; tile < ntiles; tile += gridDim.x) {
        int row0 = tile * 64 + wave * 16;
        f32x4 acc[8];
#pragma unroll
        for (int n = 0; n < 8; n++) acc[n] = (f32x4){0.f, 0.f, 0.f, 0.f};
#pragma unroll
        for (int kb = 0; kb < DIM; kb += 32) {
            short8 a = *(const short8*)&hbf[(row0 + l15) * DIM + kb + quad * 8];
#pragma unroll
            for (int n = 0; n < 8; n++) {
                short8 b = *(const short8*)&w1t[(n * 16 + l15) * DIM + kb + quad * 8];
                acc[n] = __builtin_amdgcn_mfma_f32_16x16x32_bf16(a, b, acc[n], 0, 0, 0);
            }
        }
#pragma unroll
        for (int n = 0; n < 8; n++) {
#pragma unroll
            for (int r = 0; r < 4; r++) {
                float v = acc[n][r] + b1v[n];
                v = v > 0.f ? v : 0.f;
                h1s[wave][(quad * 4 + r) * 136 + n * 16 + l15] = f2bf(v);
            }
        }
        __syncthreads();
        f32x4 acc2[8];
#pragma unroll
        for (int n = 0; n < 8; n++) acc2[n] = (f32x4){0.f, 0.f, 0.f, 0.f};
#pragma unroll
        for (int kb = 0; kb < DIM; kb += 32) {
            short8 a2 = *(const short8*)&h1s[wave][l15 * 136 + kb + quad * 8];
#pragma unroll
            for (int n = 0; n < 8; n++) {
                short8 b = *(const short8*)&w2t[(n * 16 + l15) * DIM + kb + quad * 8];
                acc2[n] = __builtin_amdgcn_mfma_f32_16x16x32_bf16(a2, b, acc2[n], 0, 0, 0);
            }
        }
#pragma unroll
        for (int n = 0; n < 8; n++) {
#pragma unroll
            for (int r = 0; r < 4; r++) {
                int row = row0 + quad * 4 + r;
                if (row < N_NODES)
                    out[row * DIM + n * 16 + l15] = acc2[n][r] + b2v[n];
            }
        }
        __syncthreads();
    }
}

extern "C" void kernel_launch(void* const* d_in, const int* in_sizes, int n_in,
                              void* d_out, int out_size, void* d_ws, size_t ws_size,
                              hipStream_t stream) {
    const float* feat = (const float*)d_in[0];
    const int* src    = (const int*)d_in[1];
    const int* dst    = (const int*)d_in[2];
    const float* eps  = (const float*)d_in[3];
    const float* W1   = (const float*)d_in[4];
    const float* b1   = (const float*)d_in[5];
    const float* W2   = (const float*)d_in[6];
    const float* b2   = (const float*)d_in[7];
    float* out = (float*)d_out;

    char* ws = (char*)d_ws;
    int*      bincnt  = (int*)ws;                          //         2,048 B
    int*      rowptr  = (int*)(ws + 2048);                 //       401,408 B
    int*      csr     = (int*)(ws + 403456);               //    12,800,000 B
    uint32_t* binpair = (uint32_t*)(ws + 13203456);        //    16,015,360 B
    uint32_t* featbf  = (uint32_t*)(ws + 29218816);        //    25,600,000 B
    uint32_t* hbf     = (uint32_t*)(ws + 54818816);        //    25,608,192 B
    short*    w1t     = (short*)(ws + 80427008);           //        32,768 B
    short*    w2t     = (short*)(ws + 80459776);           // ends 80,492,544 B

    prep_kernel<<<12566, 256, 0, stream>>>(feat, featbf, W1, W2, w1t, w2t, bincnt);
    bin_kernel<<<(N_EDGES + EPB - 1) / EPB, 256, 0, stream>>>(src, dst, bincnt, binpair);
    csr_kernel<<<NBINS, 1024, 0, stream>>>(bincnt, binpair, rowptr, csr);
    gather_kernel<<<NPAD / 8, 256, 0, stream>>>(featbf, rowptr, csr, eps, hbf);
    mlp_kernel<<<1563, 256, 0, stream>>>((const short*)hbf, w1t, w2t, b1, b2, out);
}

// Round 4
// 359.792 us; speedup vs baseline: 1.0196x; 1.0196x over previous
//
#include <hip/hip_runtime.h>
#include <stdint.h>

#define N_NODES 100000
#define N_EDGES 3200000
#define DIM 128
#define NPAD 100032   // 1563 * 64
#define NBINS 391     // ceil(100000 / 256) -- 256 nodes per bin
#define BCAP 10240    // bin capacity; mean 8192
#define EPB 4096      // edges per bin_kernel block (16/thread)
#define PASSU32 3200000   // u32 per pass table: 100000 nodes * 32 u32 (64 dims)

typedef short short8 __attribute__((ext_vector_type(8)));
typedef float f32x4 __attribute__((ext_vector_type(4)));
typedef float f32x2 __attribute__((ext_vector_type(2)));

__device__ __forceinline__ short f2bf(float x) {
    uint32_t u = __builtin_bit_cast(uint32_t, x);
    u += 0x7fffu + ((u >> 16) & 1u);   // round-to-nearest-even
    return (short)(u >> 16);
}
__device__ __forceinline__ float bflo(uint32_t p) {
    return __builtin_bit_cast(float, p << 16);
}
__device__ __forceinline__ float bfhi(uint32_t p) {
    return __builtin_bit_cast(float, p & 0xffff0000u);
}
__device__ __forceinline__ uint32_t pack2(float x, float y) {
    return (uint32_t)(uint16_t)f2bf(x) | ((uint32_t)(uint16_t)f2bf(y) << 16);
}
__device__ __forceinline__ f32x2 up2(uint32_t p) {
    return (f32x2){ bflo(p), bfhi(p) };
}

// ---- K1: fused prep: feat->bf16 cast (PASS-MAJOR), W transpose, zero ----
// featp layout: featp[p][node][32 u32]  (p-th 64-dim half, 128 B per row)
__global__ __launch_bounds__(256) void prep_kernel(const float* __restrict__ feat,
                                                   uint32_t* __restrict__ featp,
                                                   const float* __restrict__ w1,
                                                   const float* __restrict__ w2,
                                                   short* __restrict__ w1t,
                                                   short* __restrict__ w2t,
                                                   int* __restrict__ bincnt) {
    int b = blockIdx.x, t = threadIdx.x;
    if (b < 12500) {                       // cast: 3.2M float4s
        int i = b * 256 + t;
        float4 f = ((const float4*)feat)[i];
        int node = i >> 5;                 // 32 float4s per 128-dim row
        int qi = i & 31;                   // which float4 in row
        int p = qi >> 4;                   // dim half
        int ld = qi & 15;                  // float4 within half (16 per half)
        uint32_t* o = &featp[p * PASSU32 + node * 32 + ld * 2];
        o[0] = pack2(f.x, f.y);
        o[1] = pack2(f.z, f.w);
    } else if (b < 12564) {                // weight transpose: 16384 elems
        int i = (b - 12500) * 256 + t;
        int k = i >> 7, n = i & 127;
        w1t[n * DIM + k] = f2bf(w1[i]);
        w2t[n * DIM + k] = f2bf(w2[i]);
    } else {                               // zero bincnt (512 ints over 2 blocks)
        int i = (b - 12564) * 256 + t;
        bincnt[i] = 0;
    }
}

// ---- K3a: bin edges by dst>>8, LDS counting-sort, coalesced write-out ---
__global__ __launch_bounds__(256) void bin_kernel(const int* __restrict__ src,
                                                  const int* __restrict__ dst,
                                                  int* __restrict__ bincnt,
                                                  uint32_t* __restrict__ binpair) {
    __shared__ int hist[512];
    __shared__ int scanv[512];
    __shared__ int scan256[256];
    __shared__ int gbase[NBINS];
    __shared__ int cursor[NBINS];
    __shared__ uint32_t sorted[EPB];
    __shared__ int saddr[EPB];
    int t = threadIdx.x;
    for (int i = t; i < 512; i += 256) hist[i] = 0;
    __syncthreads();
    int e0 = blockIdx.x * EPB;
    int nn = min(EPB, N_EDGES - e0);
    int d[16];
#pragma unroll
    for (int i = 0; i < 16; i++) {
        int idx = i * 256 + t;
        d[i] = (idx < nn) ? dst[e0 + idx] : -1;
        if (d[i] >= 0) atomicAdd(&hist[d[i] >> 8], 1);
    }
    __syncthreads();
    int h0 = hist[2 * t], h1 = hist[2 * t + 1];
    scan256[t] = h0 + h1;
    __syncthreads();
    for (int dd = 1; dd < 256; dd <<= 1) {
        int v = (t >= dd) ? scan256[t - dd] : 0;
        __syncthreads();
        scan256[t] += v;
        __syncthreads();
    }
    int pairExcl = scan256[t] - (h0 + h1);
    scanv[2 * t] = pairExcl;
    scanv[2 * t + 1] = pairExcl + h0;
    for (int b = t; b < NBINS; b += 256) {
        int h = hist[b];
        gbase[b] = h ? atomicAdd(&bincnt[b], h) : 0;
        cursor[b] = 0;
    }
    __syncthreads();
#pragma unroll
    for (int i = 0; i < 16; i++) {
        if (d[i] >= 0) {
            int b = d[i] >> 8;
            int slot = atomicAdd(&cursor[b], 1);
            int p = scanv[b] + slot;
            int g = gbase[b] + slot;
            int e = e0 + i * 256 + t;
            sorted[p] = (uint32_t)src[e] | ((uint32_t)(d[i] & 255) << 24);
            saddr[p] = (g < BCAP) ? (b * BCAP + g) : -1;
        }
    }
    __syncthreads();
    for (int i = t; i < nn; i += 256) {
        int a = saddr[i];
        if (a >= 0) binpair[a] = sorted[i];
    }
}

// ---- K3b: per-bin counting sort -> CSR (1024 thr, LDS-staged coalesced) -
__global__ __launch_bounds__(1024) void csr_kernel(const int* __restrict__ bincnt,
                                                   const uint32_t* __restrict__ binpair,
                                                   int* __restrict__ rowptr,
                                                   int* __restrict__ csr) {
    __shared__ int hist[256];
    __shared__ int cursor[256];
    __shared__ int sc[256];
    __shared__ int red[256];
    __shared__ int binbase_s;
    __shared__ int sorted_s[BCAP];
    int b = blockIdx.x;
    int t = threadIdx.x;
    if (t < 256) {
        int partial = 0;
        for (int j = t; j < b; j += 256) partial += min(bincnt[j], BCAP);
        red[t] = partial;
        hist[t] = 0;
    }
    __syncthreads();
    for (int dd = 128; dd > 0; dd >>= 1) {
        if (t < dd) red[t] += red[t + dd];
        __syncthreads();
    }
    if (t == 0) binbase_s = red[0];
    __syncthreads();
    int binbase = binbase_s;
    int cntb = min(bincnt[b], BCAP);
    const uint32_t* pairs = binpair + (size_t)b * BCAP;
    for (int i = t; i < cntb; i += 1024)
        atomicAdd(&hist[pairs[i] >> 24], 1);
    __syncthreads();
    int val = 0;
    if (t < 256) { val = hist[t]; sc[t] = val; }
    __syncthreads();
    for (int dd = 1; dd < 256; dd <<= 1) {
        int addv = (t < 256 && t >= dd) ? sc[t - dd] : 0;
        __syncthreads();
        if (t < 256) sc[t] += addv;
        __syncthreads();
    }
    if (t < 256) {
        int excl = sc[t] - val;
        rowptr[(b << 8) + t] = binbase + excl;
        cursor[t] = excl;
    }
    __syncthreads();
    for (int i = t; i < cntb; i += 1024) {
        uint32_t p = pairs[i];
        int s2 = atomicAdd(&cursor[p >> 24], 1);
        sorted_s[s2] = (int)(p & 0x00FFFFFFu);
    }
    __syncthreads();
    for (int i = t; i < cntb; i += 1024)
        csr[binbase + i] = sorted_s[i];
}

// load helper: broadcast row index from lane `sl`, load 16B of 128B row
#define LDQ(qv, sl) do { int _i = __shfl(u, (sl)); \
    qv = *(const uint4*)&featp[_i * 32 + col8 * 4]; } while (0)

#define ACC8(q) do { \
    A01 += up2((q).x); A23 += up2((q).y); A45 += up2((q).z); A67 += up2((q).w); } while (0)

// ---- K4: dim-split 2-pass gather; 8 rows per dwordx4 instruction --------
// pass p reads featp table p (12.8 MB working set) and writes hbf half-row
__global__ __launch_bounds__(256) void gather_kernel(const uint32_t* __restrict__ featp,
                                                     const int* __restrict__ rowptr,
                                                     const int* __restrict__ csr,
                                                     const float* __restrict__ eps,
                                                     uint32_t* __restrict__ hbf,
                                                     int poff) {   // p*32 (u32 offset in hbf row)
    int wid = blockIdx.x * 4 + (threadIdx.x >> 6);
    int lane = threadIdx.x & 63;
    int eighth = lane >> 3;     // which of 8 rows in a load instruction
    int col8 = lane & 7;        // uint4 column: 8 lanes x 16B = 128B row
    if (wid >= N_NODES) {       // padding rows for the MLP tile
        if (wid < NPAD && lane < 32) hbf[wid * 64 + poff + lane] = 0;
        return;
    }
    float e1 = 1.0f + eps[0];
    uint4 sf = *(const uint4*)&featp[wid * 32 + col8 * 4];  // self half-row
    f32x2 A01 = (f32x2){0.f, 0.f}, A23 = (f32x2){0.f, 0.f};
    f32x2 A45 = (f32x2){0.f, 0.f}, A67 = (f32x2){0.f, 0.f};
    int start = rowptr[wid], end = rowptr[wid + 1];
    for (int base = start; base < end; base += 64) {
        int m = min(64, end - base);
        int u = (lane < m) ? csr[base + lane] : 0;
        int j = 0;
        for (; j + 32 <= m; j += 32) {   // full 32-edge chunk: 4 instrs, 4 KB
            uint4 q0, q1, q2, q3;
            LDQ(q0, j + eighth);
            LDQ(q1, j + 8 + eighth);
            LDQ(q2, j + 16 + eighth);
            LDQ(q3, j + 24 + eighth);
            ACC8(q0); ACC8(q1); ACC8(q2); ACC8(q3);
        }
        int r = m - j;
        if (r > 0) {                      // graded tail: 4/3/2/1 instructions
            int mm = m - 1;
            if (r > 24) {
                uint4 q0, q1, q2, q3;
                int p3 = j + 24 + eighth;
                LDQ(q0, j + eighth); LDQ(q1, j + 8 + eighth);
                LDQ(q2, j + 16 + eighth); LDQ(q3, min(p3, mm));
                ACC8(q0); ACC8(q1); ACC8(q2);
                if (p3 < m) ACC8(q3);
            } else if (r > 16) {
                uint4 q0, q1, q2;
                int p2 = j + 16 + eighth;
                LDQ(q0, j + eighth); LDQ(q1, j + 8 + eighth);
                LDQ(q2, min(p2, mm));
                ACC8(q0); ACC8(q1);
                if (p2 < m) ACC8(q2);
            } else if (r > 8) {
                uint4 q0, q1;
                int p1 = j + 8 + eighth;
                LDQ(q0, j + eighth); LDQ(q1, min(p1, mm));
                ACC8(q0);
                if (p1 < m) ACC8(q1);
            } else {
                uint4 q0;
                int p0 = j + eighth;
                LDQ(q0, min(p0, mm));
                if (p0 < m) ACC8(q0);
            }
        }
    }
    // reduce across the 8 row-groups (xor 8, 16, 32)
    float a0 = A01.x, a1 = A01.y, a2 = A23.x, a3 = A23.y;
    float a4 = A45.x, a5 = A45.y, a6 = A67.x, a7 = A67.y;
    a0 += __shfl_xor(a0, 8);  a1 += __shfl_xor(a1, 8);
    a2 += __shfl_xor(a2, 8);  a3 += __shfl_xor(a3, 8);
    a4 += __shfl_xor(a4, 8);  a5 += __shfl_xor(a5, 8);
    a6 += __shfl_xor(a6, 8);  a7 += __shfl_xor(a7, 8);
    a0 += __shfl_xor(a0, 16); a1 += __shfl_xor(a1, 16);
    a2 += __shfl_xor(a2, 16); a3 += __shfl_xor(a3, 16);
    a4 += __shfl_xor(a4, 16); a5 += __shfl_xor(a5, 16);
    a6 += __shfl_xor(a6, 16); a7 += __shfl_xor(a7, 16);
    a0 += __shfl_xor(a0, 32); a1 += __shfl_xor(a1, 32);
    a2 += __shfl_xor(a2, 32); a3 += __shfl_xor(a3, 32);
    a4 += __shfl_xor(a4, 32); a5 += __shfl_xor(a5, 32);
    a6 += __shfl_xor(a6, 32); a7 += __shfl_xor(a7, 32);
    if (eighth == 0) {         // lanes 0-7 store the 128B half-row
        a0 += e1 * bflo(sf.x); a1 += e1 * bfhi(sf.x);
        a2 += e1 * bflo(sf.y); a3 += e1 * bfhi(sf.y);
        a4 += e1 * bflo(sf.z); a5 += e1 * bfhi(sf.z);
        a6 += e1 * bflo(sf.w); a7 += e1 * bfhi(sf.w);
        uint4 w;
        w.x = pack2(a0, a1); w.y = pack2(a2, a3);
        w.z = pack2(a4, a5); w.w = pack2(a6, a7);
        *(uint4*)&hbf[wid * 64 + poff + col8 * 4] = w;
    }
}

// ---- K5: fused 2-layer MLP via bf16 MFMA 16x16x32 -----------------------
__global__ __launch_bounds__(256) void mlp_kernel(const short* __restrict__ hbf,
                                                  const short* __restrict__ w1t,
                                                  const short* __restrict__ w2t,
                                                  const float* __restrict__ b1,
                                                  const float* __restrict__ b2,
                                                  float* __restrict__ out) {
    __shared__ __align__(16) short h1s[4][16 * 136];
    const int wave = threadIdx.x >> 6;
    const int lane = threadIdx.x & 63;
    const int l15 = lane & 15;
    const int quad = lane >> 4;

    float b1v[8], b2v[8];
#pragma unroll
    for (int n = 0; n < 8; n++) {
        b1v[n] = b1[n * 16 + l15];
        b2v[n] = b2[n * 16 + l15];
    }

    const int ntiles = NPAD / 64;
    for (int tile = blockIdx.x; tile < ntiles; tile += gridDim.x) {
        int row0 = tile * 64 + wave * 16;
        f32x4 acc[8];
#pragma unroll
        for (int n = 0; n < 8; n++) acc[n] = (f32x4){0.f, 0.f, 0.f, 0.f};
#pragma unroll
        for (int kb = 0; kb < DIM; kb += 32) {
            short8 a = *(const short8*)&hbf[(row0 + l15) * DIM + kb + quad * 8];
#pragma unroll
            for (int n = 0; n < 8; n++) {
                short8 b = *(const short8*)&w1t[(n * 16 + l15) * DIM + kb + quad * 8];
                acc[n] = __builtin_amdgcn_mfma_f32_16x16x32_bf16(a, b, acc[n], 0, 0, 0);
            }
        }
#pragma unroll
        for (int n = 0; n < 8; n++) {
#pragma unroll
            for (int r = 0; r < 4; r++) {
                float v = acc[n][r] + b1v[n];
                v = v > 0.f ? v : 0.f;
                h1s[wave][(quad * 4 + r) * 136 + n * 16 + l15] = f2bf(v);
            }
        }
        __syncthreads();
        f32x4 acc2[8];
#pragma unroll
        for (int n = 0; n < 8; n++) acc2[n] = (f32x4){0.f, 0.f, 0.f, 0.f};
#pragma unroll
        for (int kb = 0; kb < DIM; kb += 32) {
            short8 a2 = *(const short8*)&h1s[wave][l15 * 136 + kb + quad * 8];
#pragma unroll
            for (int n = 0; n < 8; n++) {
                short8 b = *(const short8*)&w2t[(n * 16 + l15) * DIM + kb + quad * 8];
                acc2[n] = __builtin_amdgcn_mfma_f32_16x16x32_bf16(a2, b, acc2[n], 0, 0, 0);
            }
        }
#pragma unroll
        for (int n = 0; n < 8; n++) {
#pragma unroll
            for (int r = 0; r < 4; r++) {
                int row = row0 + quad * 4 + r;
                if (row < N_NODES)
                    out[row * DIM + n * 16 + l15] = acc2[n][r] + b2v[n];
            }
        }
        __syncthreads();
    }
}

extern "C" void kernel_launch(void* const* d_in, const int* in_sizes, int n_in,
                              void* d_out, int out_size, void* d_ws, size_t ws_size,
                              hipStream_t stream) {
    const float* feat = (const float*)d_in[0];
    const int* src    = (const int*)d_in[1];
    const int* dst    = (const int*)d_in[2];
    const float* eps  = (const float*)d_in[3];
    const float* W1   = (const float*)d_in[4];
    const float* b1   = (const float*)d_in[5];
    const float* W2   = (const float*)d_in[6];
    const float* b2   = (const float*)d_in[7];
    float* out = (float*)d_out;

    char* ws = (char*)d_ws;
    int*      bincnt  = (int*)ws;                          //         2,048 B
    int*      rowptr  = (int*)(ws + 2048);                 //       401,408 B
    int*      csr     = (int*)(ws + 403456);               //    12,800,000 B
    uint32_t* binpair = (uint32_t*)(ws + 13203456);        //    16,015,360 B
    uint32_t* featp   = (uint32_t*)(ws + 29218816);        //    25,600,000 B (2 pass tables)
    uint32_t* hbf     = (uint32_t*)(ws + 54818816);        //    25,608,192 B
    short*    w1t     = (short*)(ws + 80427008);           //        32,768 B
    short*    w2t     = (short*)(ws + 80459776);           // ends 80,492,544 B

    prep_kernel<<<12566, 256, 0, stream>>>(feat, featp, W1, W2, w1t, w2t, bincnt);
    bin_kernel<<<(N_EDGES + EPB - 1) / EPB, 256, 0, stream>>>(src, dst, bincnt, binpair);
    csr_kernel<<<NBINS, 1024, 0, stream>>>(bincnt, binpair, rowptr, csr);
    gather_kernel<<<NPAD / 4, 256, 0, stream>>>(featp, rowptr, csr, eps, hbf, 0);
    gather_kernel<<<NPAD / 4, 256, 0, stream>>>(featp + PASSU32, rowptr, csr, eps, hbf, 32);
    mlp_kernel<<<1563, 256, 0, stream>>>((const short*)hbf, w1t, w2t, b1, b2, out);
}

// Round 5
// 310.232 us; speedup vs baseline: 1.1824x; 1.1598x over previous
//
#include <hip/hip_runtime.h>
#include <stdint.h>

#define N_NODES 100000
#define N_EDGES 3200000
#define DIM 128
#define NPAD 100032   // 1563 * 64
#define NBINS 391     // ceil(100000 / 256) -- 256 nodes per bin
#define BCAP 10240    // bin capacity; mean 8192
#define EPB 4096      // edges per bin_kernel block (16/thread)
#define PASSU32 3200000   // u32 per pass table: 100000 nodes * 32 u32 (64 dims)
#define WSTR 140      // LDS row stride in shorts (280 B) -> ~2-way banks, free

typedef short short8 __attribute__((ext_vector_type(8)));
typedef float f32x4 __attribute__((ext_vector_type(4)));
typedef float f32x2 __attribute__((ext_vector_type(2)));

__device__ __forceinline__ short f2bf(float x) {
    uint32_t u = __builtin_bit_cast(uint32_t, x);
    u += 0x7fffu + ((u >> 16) & 1u);   // round-to-nearest-even
    return (short)(u >> 16);
}
__device__ __forceinline__ float bflo(uint32_t p) {
    return __builtin_bit_cast(float, p << 16);
}
__device__ __forceinline__ float bfhi(uint32_t p) {
    return __builtin_bit_cast(float, p & 0xffff0000u);
}
__device__ __forceinline__ uint32_t pack2(float x, float y) {
    return (uint32_t)(uint16_t)f2bf(x) | ((uint32_t)(uint16_t)f2bf(y) << 16);
}
__device__ __forceinline__ f32x2 up2(uint32_t p) {
    return (f32x2){ bflo(p), bfhi(p) };
}

// ---- K1: fused prep: feat->bf16 cast (PASS-MAJOR), W transpose, zero ----
// featp layout: featp[p][node][32 u32]  (p-th 64-dim half, 128 B per row)
__global__ __launch_bounds__(256) void prep_kernel(const float* __restrict__ feat,
                                                   uint32_t* __restrict__ featp,
                                                   const float* __restrict__ w1,
                                                   const float* __restrict__ w2,
                                                   short* __restrict__ w1t,
                                                   short* __restrict__ w2t,
                                                   int* __restrict__ bincnt) {
    int b = blockIdx.x, t = threadIdx.x;
    if (b < 12500) {                       // cast: 3.2M float4s
        int i = b * 256 + t;
        float4 f = ((const float4*)feat)[i];
        int node = i >> 5;                 // 32 float4s per 128-dim row
        int qi = i & 31;                   // which float4 in row
        int p = qi >> 4;                   // dim half
        int ld = qi & 15;                  // float4 within half (16 per half)
        uint32_t* o = &featp[p * PASSU32 + node * 32 + ld * 2];
        o[0] = pack2(f.x, f.y);
        o[1] = pack2(f.z, f.w);
    } else if (b < 12564) {                // weight transpose: 16384 elems
        int i = (b - 12500) * 256 + t;
        int k = i >> 7, n = i & 127;
        w1t[n * DIM + k] = f2bf(w1[i]);
        w2t[n * DIM + k] = f2bf(w2[i]);
    } else {                               // zero bincnt (512 ints over 2 blocks)
        int i = (b - 12564) * 256 + t;
        bincnt[i] = 0;
    }
}

// ---- K3a: bin edges by dst>>8, LDS counting-sort, coalesced write-out ---
__global__ __launch_bounds__(256) void bin_kernel(const int* __restrict__ src,
                                                  const int* __restrict__ dst,
                                                  int* __restrict__ bincnt,
                                                  uint32_t* __restrict__ binpair) {
    __shared__ int hist[512];
    __shared__ int scanv[512];
    __shared__ int scan256[256];
    __shared__ int gbase[NBINS];
    __shared__ int cursor[NBINS];
    __shared__ uint32_t sorted[EPB];
    __shared__ int saddr[EPB];
    int t = threadIdx.x;
    for (int i = t; i < 512; i += 256) hist[i] = 0;
    __syncthreads();
    int e0 = blockIdx.x * EPB;
    int nn = min(EPB, N_EDGES - e0);
    int d[16];
#pragma unroll
    for (int i = 0; i < 16; i++) {
        int idx = i * 256 + t;
        d[i] = (idx < nn) ? dst[e0 + idx] : -1;
        if (d[i] >= 0) atomicAdd(&hist[d[i] >> 8], 1);
    }
    __syncthreads();
    int h0 = hist[2 * t], h1 = hist[2 * t + 1];
    scan256[t] = h0 + h1;
    __syncthreads();
    for (int dd = 1; dd < 256; dd <<= 1) {
        int v = (t >= dd) ? scan256[t - dd] : 0;
        __syncthreads();
        scan256[t] += v;
        __syncthreads();
    }
    int pairExcl = scan256[t] - (h0 + h1);
    scanv[2 * t] = pairExcl;
    scanv[2 * t + 1] = pairExcl + h0;
    for (int b = t; b < NBINS; b += 256) {
        int h = hist[b];
        gbase[b] = h ? atomicAdd(&bincnt[b], h) : 0;
        cursor[b] = 0;
    }
    __syncthreads();
#pragma unroll
    for (int i = 0; i < 16; i++) {
        if (d[i] >= 0) {
            int b = d[i] >> 8;
            int slot = atomicAdd(&cursor[b], 1);
            int p = scanv[b] + slot;
            int g = gbase[b] + slot;
            int e = e0 + i * 256 + t;
            sorted[p] = (uint32_t)src[e] | ((uint32_t)(d[i] & 255) << 24);
            saddr[p] = (g < BCAP) ? (b * BCAP + g) : -1;
        }
    }
    __syncthreads();
    for (int i = t; i < nn; i += 256) {
        int a = saddr[i];
        if (a >= 0) binpair[a] = sorted[i];
    }
}

// ---- K3b: per-bin counting sort -> CSR (1024 thr, LDS-staged coalesced) -
__global__ __launch_bounds__(1024) void csr_kernel(const int* __restrict__ bincnt,
                                                   const uint32_t* __restrict__ binpair,
                                                   int* __restrict__ rowptr,
                                                   int* __restrict__ csr) {
    __shared__ int hist[256];
    __shared__ int cursor[256];
    __shared__ int sc[256];
    __shared__ int red[256];
    __shared__ int binbase_s;
    __shared__ int sorted_s[BCAP];
    int b = blockIdx.x;
    int t = threadIdx.x;
    if (t < 256) {
        int partial = 0;
        for (int j = t; j < b; j += 256) partial += min(bincnt[j], BCAP);
        red[t] = partial;
        hist[t] = 0;
    }
    __syncthreads();
    for (int dd = 128; dd > 0; dd >>= 1) {
        if (t < dd) red[t] += red[t + dd];
        __syncthreads();
    }
    if (t == 0) binbase_s = red[0];
    __syncthreads();
    int binbase = binbase_s;
    int cntb = min(bincnt[b], BCAP);
    const uint32_t* pairs = binpair + (size_t)b * BCAP;
    for (int i = t; i < cntb; i += 1024)
        atomicAdd(&hist[pairs[i] >> 24], 1);
    __syncthreads();
    int val = 0;
    if (t < 256) { val = hist[t]; sc[t] = val; }
    __syncthreads();
    for (int dd = 1; dd < 256; dd <<= 1) {
        int addv = (t < 256 && t >= dd) ? sc[t - dd] : 0;
        __syncthreads();
        if (t < 256) sc[t] += addv;
        __syncthreads();
    }
    if (t < 256) {
        int excl = sc[t] - val;
        rowptr[(b << 8) + t] = binbase + excl;
        cursor[t] = excl;
    }
    __syncthreads();
    for (int i = t; i < cntb; i += 1024) {
        uint32_t p = pairs[i];
        int s2 = atomicAdd(&cursor[p >> 24], 1);
        sorted_s[s2] = (int)(p & 0x00FFFFFFu);
    }
    __syncthreads();
    for (int i = t; i < cntb; i += 1024)
        csr[binbase + i] = sorted_s[i];
}

// load helper: broadcast row index from lane `sl`, load 16B of 128B row
#define LDQ(qv, sl) do { int _i = __shfl(u, (sl)); \
    qv = *(const uint4*)&featp[_i * 32 + col8 * 4]; } while (0)

#define ACC8(q) do { \
    A01 += up2((q).x); A23 += up2((q).y); A45 += up2((q).z); A67 += up2((q).w); } while (0)

// ---- K4: dim-split 2-pass gather; 8 rows per dwordx4 instruction --------
// pass p reads featp table p (12.8 MB working set) and writes hbf half-row
__global__ __launch_bounds__(256) void gather_kernel(const uint32_t* __restrict__ featp,
                                                     const int* __restrict__ rowptr,
                                                     const int* __restrict__ csr,
                                                     const float* __restrict__ eps,
                                                     uint32_t* __restrict__ hbf,
                                                     int poff) {   // p*32 (u32 offset in hbf row)
    int wid = blockIdx.x * 4 + (threadIdx.x >> 6);
    int lane = threadIdx.x & 63;
    int eighth = lane >> 3;     // which of 8 rows in a load instruction
    int col8 = lane & 7;        // uint4 column: 8 lanes x 16B = 128B row
    if (wid >= N_NODES) {       // padding rows for the MLP tile
        if (wid < NPAD && lane < 32) hbf[wid * 64 + poff + lane] = 0;
        return;
    }
    float e1 = 1.0f + eps[0];
    uint4 sf = *(const uint4*)&featp[wid * 32 + col8 * 4];  // self half-row
    f32x2 A01 = (f32x2){0.f, 0.f}, A23 = (f32x2){0.f, 0.f};
    f32x2 A45 = (f32x2){0.f, 0.f}, A67 = (f32x2){0.f, 0.f};
    int start = rowptr[wid], end = rowptr[wid + 1];
    for (int base = start; base < end; base += 64) {
        int m = min(64, end - base);
        int u = (lane < m) ? csr[base + lane] : 0;
        int j = 0;
        for (; j + 32 <= m; j += 32) {   // full 32-edge chunk: 4 instrs, 4 KB
            uint4 q0, q1, q2, q3;
            LDQ(q0, j + eighth);
            LDQ(q1, j + 8 + eighth);
            LDQ(q2, j + 16 + eighth);
            LDQ(q3, j + 24 + eighth);
            ACC8(q0); ACC8(q1); ACC8(q2); ACC8(q3);
        }
        int r = m - j;
        if (r > 0) {                      // graded tail: 4/3/2/1 instructions
            int mm = m - 1;
            if (r > 24) {
                uint4 q0, q1, q2, q3;
                int p3 = j + 24 + eighth;
                LDQ(q0, j + eighth); LDQ(q1, j + 8 + eighth);
                LDQ(q2, j + 16 + eighth); LDQ(q3, min(p3, mm));
                ACC8(q0); ACC8(q1); ACC8(q2);
                if (p3 < m) ACC8(q3);
            } else if (r > 16) {
                uint4 q0, q1, q2;
                int p2 = j + 16 + eighth;
                LDQ(q0, j + eighth); LDQ(q1, j + 8 + eighth);
                LDQ(q2, min(p2, mm));
                ACC8(q0); ACC8(q1);
                if (p2 < m) ACC8(q2);
            } else if (r > 8) {
                uint4 q0, q1;
                int p1 = j + 8 + eighth;
                LDQ(q0, j + eighth); LDQ(q1, min(p1, mm));
                ACC8(q0);
                if (p1 < m) ACC8(q1);
            } else {
                uint4 q0;
                int p0 = j + eighth;
                LDQ(q0, min(p0, mm));
                if (p0 < m) ACC8(q0);
            }
        }
    }
    // reduce across the 8 row-groups (xor 8, 16, 32)
    float a0 = A01.x, a1 = A01.y, a2 = A23.x, a3 = A23.y;
    float a4 = A45.x, a5 = A45.y, a6 = A67.x, a7 = A67.y;
    a0 += __shfl_xor(a0, 8);  a1 += __shfl_xor(a1, 8);
    a2 += __shfl_xor(a2, 8);  a3 += __shfl_xor(a3, 8);
    a4 += __shfl_xor(a4, 8);  a5 += __shfl_xor(a5, 8);
    a6 += __shfl_xor(a6, 8);  a7 += __shfl_xor(a7, 8);
    a0 += __shfl_xor(a0, 16); a1 += __shfl_xor(a1, 16);
    a2 += __shfl_xor(a2, 16); a3 += __shfl_xor(a3, 16);
    a4 += __shfl_xor(a4, 16); a5 += __shfl_xor(a5, 16);
    a6 += __shfl_xor(a6, 16); a7 += __shfl_xor(a7, 16);
    a0 += __shfl_xor(a0, 32); a1 += __shfl_xor(a1, 32);
    a2 += __shfl_xor(a2, 32); a3 += __shfl_xor(a3, 32);
    a4 += __shfl_xor(a4, 32); a5 += __shfl_xor(a5, 32);
    a6 += __shfl_xor(a6, 32); a7 += __shfl_xor(a7, 32);
    if (eighth == 0) {         // lanes 0-7 store the 128B half-row
        a0 += e1 * bflo(sf.x); a1 += e1 * bfhi(sf.x);
        a2 += e1 * bflo(sf.y); a3 += e1 * bfhi(sf.y);
        a4 += e1 * bflo(sf.z); a5 += e1 * bfhi(sf.z);
        a6 += e1 * bflo(sf.w); a7 += e1 * bfhi(sf.w);
        uint4 w;
        w.x = pack2(a0, a1); w.y = pack2(a2, a3);
        w.z = pack2(a4, a5); w.w = pack2(a6, a7);
        *(uint4*)&hbf[wid * 64 + poff + col8 * 4] = w;
    }
}

// ---- K5: fused 2-layer MLP; weights staged ONCE in LDS, 8 indep waves ---
// 256 blocks x 512 thr, 1 block/CU. LDS: 2x35840 (weights) + 8x4480 (h1)
__global__ __launch_bounds__(512) void mlp_kernel(const short* __restrict__ hbf,
                                                  const short* __restrict__ w1t,
                                                  const short* __restrict__ w2t,
                                                  const float* __restrict__ b1,
                                                  const float* __restrict__ b2,
                                                  float* __restrict__ out) {
    __shared__ __align__(16) short w1s[128 * WSTR];
    __shared__ __align__(16) short w2s[128 * WSTR];
    __shared__ __align__(16) short h1s[8][16 * WSTR];
    const int t = threadIdx.x;
    // stage both weight tables into LDS (once per block)
    for (int c = t; c < 2048; c += 512) {          // 2048 short8 chunks/table
        int row = c >> 4, cp = c & 15;
        *(short8*)&w1s[row * WSTR + cp * 8] = *(const short8*)&w1t[row * DIM + cp * 8];
        *(short8*)&w2s[row * WSTR + cp * 8] = *(const short8*)&w2t[row * DIM + cp * 8];
    }
    const int wave = t >> 6;
    const int lane = t & 63;
    const int l15 = lane & 15;
    const int quad = lane >> 4;
    short* h1w = &h1s[wave][0];

    float b1v[8], b2v[8];
#pragma unroll
    for (int n = 0; n < 8; n++) {
        b1v[n] = b1[n * 16 + l15];
        b2v[n] = b2[n * 16 + l15];
    }
    __syncthreads();   // weights staged; waves independent from here on

    const int ngroups = NPAD / 16;                 // 6252 16-row groups
    for (int g = blockIdx.x * 8 + wave; g < ngroups; g += gridDim.x * 8) {
        int row0 = g * 16;
        f32x4 acc[8];
#pragma unroll
        for (int n = 0; n < 8; n++) acc[n] = (f32x4){0.f, 0.f, 0.f, 0.f};
#pragma unroll
        for (int kb = 0; kb < DIM; kb += 32) {
            short8 a = *(const short8*)&hbf[(row0 + l15) * DIM + kb + quad * 8];
#pragma unroll
            for (int n = 0; n < 8; n++) {
                short8 b = *(const short8*)&w1s[(n * 16 + l15) * WSTR + kb + quad * 8];
                acc[n] = __builtin_amdgcn_mfma_f32_16x16x32_bf16(a, b, acc[n], 0, 0, 0);
            }
        }
#pragma unroll
        for (int n = 0; n < 8; n++) {
#pragma unroll
            for (int r = 0; r < 4; r++) {
                float v = acc[n][r] + b1v[n];
                v = v > 0.f ? v : 0.f;
                h1w[(quad * 4 + r) * WSTR + n * 16 + l15] = f2bf(v);
            }
        }
        // same-wave LDS RAW: compiler inserts lgkmcnt wait (no barrier needed)
        f32x4 acc2[8];
#pragma unroll
        for (int n = 0; n < 8; n++) acc2[n] = (f32x4){0.f, 0.f, 0.f, 0.f};
#pragma unroll
        for (int kb = 0; kb < DIM; kb += 32) {
            short8 a2 = *(const short8*)&h1w[l15 * WSTR + kb + quad * 8];
#pragma unroll
            for (int n = 0; n < 8; n++) {
                short8 b = *(const short8*)&w2s[(n * 16 + l15) * WSTR + kb + quad * 8];
                acc2[n] = __builtin_amdgcn_mfma_f32_16x16x32_bf16(a2, b, acc2[n], 0, 0, 0);
            }
        }
#pragma unroll
        for (int n = 0; n < 8; n++) {
#pragma unroll
            for (int r = 0; r < 4; r++) {
                int row = row0 + quad * 4 + r;
                if (row < N_NODES)
                    out[row * DIM + n * 16 + l15] = acc2[n][r] + b2v[n];
            }
        }
    }
}

extern "C" void kernel_launch(void* const* d_in, const int* in_sizes, int n_in,
                              void* d_out, int out_size, void* d_ws, size_t ws_size,
                              hipStream_t stream) {
    const float* feat = (const float*)d_in[0];
    const int* src    = (const int*)d_in[1];
    const int* dst    = (const int*)d_in[2];
    const float* eps  = (const float*)d_in[3];
    const float* W1   = (const float*)d_in[4];
    const float* b1   = (const float*)d_in[5];
    const float* W2   = (const float*)d_in[6];
    const float* b2   = (const float*)d_in[7];
    float* out = (float*)d_out;

    char* ws = (char*)d_ws;
    int*      bincnt  = (int*)ws;                          //         2,048 B
    int*      rowptr  = (int*)(ws + 2048);                 //       401,408 B
    int*      csr     = (int*)(ws + 403456);               //    12,800,000 B
    uint32_t* binpair = (uint32_t*)(ws + 13203456);        //    16,015,360 B
    uint32_t* featp   = (uint32_t*)(ws + 29218816);        //    25,600,000 B (2 pass tables)
    uint32_t* hbf     = (uint32_t*)(ws + 54818816);        //    25,608,192 B
    short*    w1t     = (short*)(ws + 80427008);           //        32,768 B
    short*    w2t     = (short*)(ws + 80459776);           // ends 80,492,544 B

    prep_kernel<<<12566, 256, 0, stream>>>(feat, featp, W1, W2, w1t, w2t, bincnt);
    bin_kernel<<<(N_EDGES + EPB - 1) / EPB, 256, 0, stream>>>(src, dst, bincnt, binpair);
    csr_kernel<<<NBINS, 1024, 0, stream>>>(bincnt, binpair, rowptr, csr);
    gather_kernel<<<NPAD / 4, 256, 0, stream>>>(featp, rowptr, csr, eps, hbf, 0);
    gather_kernel<<<NPAD / 4, 256, 0, stream>>>(featp + PASSU32, rowptr, csr, eps, hbf, 32);
    mlp_kernel<<<256, 512, 0, stream>>>((const short*)hbf, w1t, w2t, b1, b2, out);
}

// Round 6
// 308.543 us; speedup vs baseline: 1.1889x; 1.0055x over previous
//
#include <hip/hip_runtime.h>
#include <stdint.h>

#define N_NODES 100000
#define N_EDGES 3200000
#define DIM 128
#define NPAD 100032   // 1563 * 64
#define NBINS 391     // ceil(100000 / 256) -- 256 nodes per bin
#define BCAP 10176    // bin capacity; mean 8184, +22 sigma
#define BSTR 64       // bincnt stride in ints (256 B) -> 1 bin per cache line
#define EPB 4096      // edges per bin_kernel block (16/thread)
#define PASSU32 3200000   // u32 per pass table: 100000 nodes * 32 u32 (64 dims)
#define WSTR 140      // LDS row stride in shorts (280 B) -> ~2-way banks, free

typedef short short8 __attribute__((ext_vector_type(8)));
typedef float f32x4 __attribute__((ext_vector_type(4)));
typedef float f32x2 __attribute__((ext_vector_type(2)));

__device__ __forceinline__ short f2bf(float x) {
    uint32_t u = __builtin_bit_cast(uint32_t, x);
    u += 0x7fffu + ((u >> 16) & 1u);   // round-to-nearest-even
    return (short)(u >> 16);
}
__device__ __forceinline__ float bflo(uint32_t p) {
    return __builtin_bit_cast(float, p << 16);
}
__device__ __forceinline__ float bfhi(uint32_t p) {
    return __builtin_bit_cast(float, p & 0xffff0000u);
}
__device__ __forceinline__ uint32_t pack2(float x, float y) {
    return (uint32_t)(uint16_t)f2bf(x) | ((uint32_t)(uint16_t)f2bf(y) << 16);
}
__device__ __forceinline__ f32x2 up2(uint32_t p) {
    return (f32x2){ bflo(p), bfhi(p) };
}

// ---- K1: fused prep: feat->bf16 cast (PASS-MAJOR), W transpose, zero ----
// featp layout: featp[p][node][32 u32]  (p-th 64-dim half, 128 B per row)
__global__ __launch_bounds__(256) void prep_kernel(const float* __restrict__ feat,
                                                   uint32_t* __restrict__ featp,
                                                   const float* __restrict__ w1,
                                                   const float* __restrict__ w2,
                                                   short* __restrict__ w1t,
                                                   short* __restrict__ w2t,
                                                   int* __restrict__ bincnt) {
    int b = blockIdx.x, t = threadIdx.x;
    if (b < 12500) {                       // cast: 3.2M float4s
        int i = b * 256 + t;
        float4 f = ((const float4*)feat)[i];
        int node = i >> 5;                 // 32 float4s per 128-dim row
        int qi = i & 31;                   // which float4 in row
        int p = qi >> 4;                   // dim half
        int ld = qi & 15;                  // float4 within half (16 per half)
        uint32_t* o = &featp[p * PASSU32 + node * 32 + ld * 2];
        o[0] = pack2(f.x, f.y);
        o[1] = pack2(f.z, f.w);
    } else if (b < 12564) {                // weight transpose: 16384 elems
        int i = (b - 12500) * 256 + t;
        int k = i >> 7, n = i & 127;
        w1t[n * DIM + k] = f2bf(w1[i]);
        w2t[n * DIM + k] = f2bf(w2[i]);
    } else {                               // zero padded bincnt (25024 ints)
        int i = (b - 12564) * 256 + t;
        if (i < NBINS * BSTR) bincnt[i] = 0;
    }
}

// ---- K3a: bin edges by dst>>8, LDS counting-sort, coalesced write-out ---
__global__ __launch_bounds__(256) void bin_kernel(const int* __restrict__ src,
                                                  const int* __restrict__ dst,
                                                  int* __restrict__ bincnt,
                                                  uint32_t* __restrict__ binpair) {
    __shared__ int hist[512];
    __shared__ int scanv[512];
    __shared__ int scan256[256];
    __shared__ int gbase[NBINS];
    __shared__ int cursor[NBINS];
    __shared__ uint32_t sorted[EPB];
    __shared__ int saddr[EPB];
    int t = threadIdx.x;
    for (int i = t; i < 512; i += 256) hist[i] = 0;
    __syncthreads();
    int e0 = blockIdx.x * EPB;
    int nn = min(EPB, N_EDGES - e0);
    int d[16];
#pragma unroll
    for (int i = 0; i < 16; i++) {
        int idx = i * 256 + t;
        d[i] = (idx < nn) ? dst[e0 + idx] : -1;
        if (d[i] >= 0) atomicAdd(&hist[d[i] >> 8], 1);
    }
    __syncthreads();
    int h0 = hist[2 * t], h1 = hist[2 * t + 1];
    scan256[t] = h0 + h1;
    __syncthreads();
    for (int dd = 1; dd < 256; dd <<= 1) {
        int v = (t >= dd) ? scan256[t - dd] : 0;
        __syncthreads();
        scan256[t] += v;
        __syncthreads();
    }
    int pairExcl = scan256[t] - (h0 + h1);
    scanv[2 * t] = pairExcl;
    scanv[2 * t + 1] = pairExcl + h0;
    for (int b = t; b < NBINS; b += 256) {
        int h = hist[b];
        gbase[b] = h ? atomicAdd(&bincnt[b * BSTR], h) : 0;   // padded: 1 bin/line
        cursor[b] = 0;
    }
    __syncthreads();
#pragma unroll
    for (int i = 0; i < 16; i++) {
        if (d[i] >= 0) {
            int b = d[i] >> 8;
            int slot = atomicAdd(&cursor[b], 1);
            int p = scanv[b] + slot;
            int g = gbase[b] + slot;
            int e = e0 + i * 256 + t;
            sorted[p] = (uint32_t)src[e] | ((uint32_t)(d[i] & 255) << 24);
            saddr[p] = (g < BCAP) ? (b * BCAP + g) : -1;
        }
    }
    __syncthreads();
    for (int i = t; i < nn; i += 256) {
        int a = saddr[i];
        if (a >= 0) binpair[a] = sorted[i];
    }
}

// ---- K3b: per-bin counting sort -> CSR (1024 thr, LDS-staged coalesced) -
__global__ __launch_bounds__(1024) void csr_kernel(const int* __restrict__ bincnt,
                                                   const uint32_t* __restrict__ binpair,
                                                   int* __restrict__ rowptr,
                                                   int* __restrict__ csr) {
    __shared__ int hist[256];
    __shared__ int cursor[256];
    __shared__ int sc[256];
    __shared__ int red[256];
    __shared__ int binbase_s;
    __shared__ int sorted_s[BCAP];
    int b = blockIdx.x;
    int t = threadIdx.x;
    if (t < 256) {
        int partial = 0;
        for (int j = t; j < b; j += 256) partial += min(bincnt[j * BSTR], BCAP);
        red[t] = partial;
        hist[t] = 0;
    }
    __syncthreads();
    for (int dd = 128; dd > 0; dd >>= 1) {
        if (t < dd) red[t] += red[t + dd];
        __syncthreads();
    }
    if (t == 0) binbase_s = red[0];
    __syncthreads();
    int binbase = binbase_s;
    int cntb = min(bincnt[b * BSTR], BCAP);
    const uint32_t* pairs = binpair + (size_t)b * BCAP;
    for (int i = t; i < cntb; i += 1024)
        atomicAdd(&hist[pairs[i] >> 24], 1);
    __syncthreads();
    int val = 0;
    if (t < 256) { val = hist[t]; sc[t] = val; }
    __syncthreads();
    for (int dd = 1; dd < 256; dd <<= 1) {
        int addv = (t < 256 && t >= dd) ? sc[t - dd] : 0;
        __syncthreads();
        if (t < 256) sc[t] += addv;
        __syncthreads();
    }
    if (t < 256) {
        int excl = sc[t] - val;
        rowptr[(b << 8) + t] = binbase + excl;
        cursor[t] = excl;
    }
    __syncthreads();
    for (int i = t; i < cntb; i += 1024) {
        uint32_t p = pairs[i];
        int s2 = atomicAdd(&cursor[p >> 24], 1);
        sorted_s[s2] = (int)(p & 0x00FFFFFFu);
    }
    __syncthreads();
    for (int i = t; i < cntb; i += 1024)
        csr[binbase + i] = sorted_s[i];
}

// load helper: broadcast row index from lane `sl`, load 16B of 128B row
#define LDQ(qv, sl) do { int _i = __shfl(u, (sl)); \
    qv = *(const uint4*)&featp[_i * 32 + col8 * 4]; } while (0)

#define ACC8(q) do { \
    A01 += up2((q).x); A23 += up2((q).y); A45 += up2((q).z); A67 += up2((q).w); } while (0)

// ---- K4: dim-split 2-pass gather; 8 rows per dwordx4 instruction --------
// pass p reads featp table p (12.8 MB working set) and writes hbf half-row
__global__ __launch_bounds__(256) void gather_kernel(const uint32_t* __restrict__ featp,
                                                     const int* __restrict__ rowptr,
                                                     const int* __restrict__ csr,
                                                     const float* __restrict__ eps,
                                                     uint32_t* __restrict__ hbf,
                                                     int poff) {   // p*32 (u32 offset in hbf row)
    int wid = blockIdx.x * 4 + (threadIdx.x >> 6);
    int lane = threadIdx.x & 63;
    int eighth = lane >> 3;     // which of 8 rows in a load instruction
    int col8 = lane & 7;        // uint4 column: 8 lanes x 16B = 128B row
    if (wid >= N_NODES) {       // padding rows for the MLP tile
        if (wid < NPAD && lane < 32) hbf[wid * 64 + poff + lane] = 0;
        return;
    }
    float e1 = 1.0f + eps[0];
    uint4 sf = *(const uint4*)&featp[wid * 32 + col8 * 4];  // self half-row
    f32x2 A01 = (f32x2){0.f, 0.f}, A23 = (f32x2){0.f, 0.f};
    f32x2 A45 = (f32x2){0.f, 0.f}, A67 = (f32x2){0.f, 0.f};
    int start = rowptr[wid], end = rowptr[wid + 1];
    for (int base = start; base < end; base += 64) {
        int m = min(64, end - base);
        int u = (lane < m) ? csr[base + lane] : 0;
        int j = 0;
        for (; j + 32 <= m; j += 32) {   // full 32-edge chunk: 4 instrs, 4 KB
            uint4 q0, q1, q2, q3;
            LDQ(q0, j + eighth);
            LDQ(q1, j + 8 + eighth);
            LDQ(q2, j + 16 + eighth);
            LDQ(q3, j + 24 + eighth);
            ACC8(q0); ACC8(q1); ACC8(q2); ACC8(q3);
        }
        int r = m - j;
        if (r > 0) {                      // graded tail: 4/3/2/1 instructions
            int mm = m - 1;
            if (r > 24) {
                uint4 q0, q1, q2, q3;
                int p3 = j + 24 + eighth;
                LDQ(q0, j + eighth); LDQ(q1, j + 8 + eighth);
                LDQ(q2, j + 16 + eighth); LDQ(q3, min(p3, mm));
                ACC8(q0); ACC8(q1); ACC8(q2);
                if (p3 < m) ACC8(q3);
            } else if (r > 16) {
                uint4 q0, q1, q2;
                int p2 = j + 16 + eighth;
                LDQ(q0, j + eighth); LDQ(q1, j + 8 + eighth);
                LDQ(q2, min(p2, mm));
                ACC8(q0); ACC8(q1);
                if (p2 < m) ACC8(q2);
            } else if (r > 8) {
                uint4 q0, q1;
                int p1 = j + 8 + eighth;
                LDQ(q0, j + eighth); LDQ(q1, min(p1, mm));
                ACC8(q0);
                if (p1 < m) ACC8(q1);
            } else {
                uint4 q0;
                int p0 = j + eighth;
                LDQ(q0, min(p0, mm));
                if (p0 < m) ACC8(q0);
            }
        }
    }
    // reduce across the 8 row-groups (xor 8, 16, 32)
    float a0 = A01.x, a1 = A01.y, a2 = A23.x, a3 = A23.y;
    float a4 = A45.x, a5 = A45.y, a6 = A67.x, a7 = A67.y;
    a0 += __shfl_xor(a0, 8);  a1 += __shfl_xor(a1, 8);
    a2 += __shfl_xor(a2, 8);  a3 += __shfl_xor(a3, 8);
    a4 += __shfl_xor(a4, 8);  a5 += __shfl_xor(a5, 8);
    a6 += __shfl_xor(a6, 8);  a7 += __shfl_xor(a7, 8);
    a0 += __shfl_xor(a0, 16); a1 += __shfl_xor(a1, 16);
    a2 += __shfl_xor(a2, 16); a3 += __shfl_xor(a3, 16);
    a4 += __shfl_xor(a4, 16); a5 += __shfl_xor(a5, 16);
    a6 += __shfl_xor(a6, 16); a7 += __shfl_xor(a7, 16);
    a0 += __shfl_xor(a0, 32); a1 += __shfl_xor(a1, 32);
    a2 += __shfl_xor(a2, 32); a3 += __shfl_xor(a3, 32);
    a4 += __shfl_xor(a4, 32); a5 += __shfl_xor(a5, 32);
    a6 += __shfl_xor(a6, 32); a7 += __shfl_xor(a7, 32);
    if (eighth == 0) {         // lanes 0-7 store the 128B half-row
        a0 += e1 * bflo(sf.x); a1 += e1 * bfhi(sf.x);
        a2 += e1 * bflo(sf.y); a3 += e1 * bfhi(sf.y);
        a4 += e1 * bflo(sf.z); a5 += e1 * bfhi(sf.z);
        a6 += e1 * bflo(sf.w); a7 += e1 * bfhi(sf.w);
        uint4 w;
        w.x = pack2(a0, a1); w.y = pack2(a2, a3);
        w.z = pack2(a4, a5); w.w = pack2(a6, a7);
        *(uint4*)&hbf[wid * 64 + poff + col8 * 4] = w;
    }
}

// ---- K5: fused 2-layer MLP; weights staged ONCE in LDS, 8 indep waves ---
// 256 blocks x 512 thr, 1 block/CU. LDS: 2x35840 (weights) + 8x4480 (h1)
__global__ __launch_bounds__(512) void mlp_kernel(const short* __restrict__ hbf,
                                                  const short* __restrict__ w1t,
                                                  const short* __restrict__ w2t,
                                                  const float* __restrict__ b1,
                                                  const float* __restrict__ b2,
                                                  float* __restrict__ out) {
    __shared__ __align__(16) short w1s[128 * WSTR];
    __shared__ __align__(16) short w2s[128 * WSTR];
    __shared__ __align__(16) short h1s[8][16 * WSTR];
    const int t = threadIdx.x;
    // stage both weight tables into LDS (once per block)
    for (int c = t; c < 2048; c += 512) {          // 2048 short8 chunks/table
        int row = c >> 4, cp = c & 15;
        *(short8*)&w1s[row * WSTR + cp * 8] = *(const short8*)&w1t[row * DIM + cp * 8];
        *(short8*)&w2s[row * WSTR + cp * 8] = *(const short8*)&w2t[row * DIM + cp * 8];
    }
    const int wave = t >> 6;
    const int lane = t & 63;
    const int l15 = lane & 15;
    const int quad = lane >> 4;
    short* h1w = &h1s[wave][0];

    float b1v[8], b2v[8];
#pragma unroll
    for (int n = 0; n < 8; n++) {
        b1v[n] = b1[n * 16 + l15];
        b2v[n] = b2[n * 16 + l15];
    }
    __syncthreads();   // weights staged; waves independent from here on

    const int ngroups = NPAD / 16;                 // 6252 16-row groups
    for (int g = blockIdx.x * 8 + wave; g < ngroups; g += gridDim.x * 8) {
        int row0 = g * 16;
        f32x4 acc[8];
#pragma unroll
        for (int n = 0; n < 8; n++) acc[n] = (f32x4){0.f, 0.f, 0.f, 0.f};
#pragma unroll
        for (int kb = 0; kb < DIM; kb += 32) {
            short8 a = *(const short8*)&hbf[(row0 + l15) * DIM + kb + quad * 8];
#pragma unroll
            for (int n = 0; n < 8; n++) {
                short8 b = *(const short8*)&w1s[(n * 16 + l15) * WSTR + kb + quad * 8];
                acc[n] = __builtin_amdgcn_mfma_f32_16x16x32_bf16(a, b, acc[n], 0, 0, 0);
            }
        }
#pragma unroll
        for (int n = 0; n < 8; n++) {
#pragma unroll
            for (int r = 0; r < 4; r++) {
                float v = acc[n][r] + b1v[n];
                v = v > 0.f ? v : 0.f;
                h1w[(quad * 4 + r) * WSTR + n * 16 + l15] = f2bf(v);
            }
        }
        // same-wave LDS RAW: compiler inserts lgkmcnt wait (no barrier needed)
        f32x4 acc2[8];
#pragma unroll
        for (int n = 0; n < 8; n++) acc2[n] = (f32x4){0.f, 0.f, 0.f, 0.f};
#pragma unroll
        for (int kb = 0; kb < DIM; kb += 32) {
            short8 a2 = *(const short8*)&h1w[l15 * WSTR + kb + quad * 8];
#pragma unroll
            for (int n = 0; n < 8; n++) {
                short8 b = *(const short8*)&w2s[(n * 16 + l15) * WSTR + kb + quad * 8];
                acc2[n] = __builtin_amdgcn_mfma_f32_16x16x32_bf16(a2, b, acc2[n], 0, 0, 0);
            }
        }
#pragma unroll
        for (int n = 0; n < 8; n++) {
#pragma unroll
            for (int r = 0; r < 4; r++) {
                int row = row0 + quad * 4 + r;
                if (row < N_NODES)
                    out[row * DIM + n * 16 + l15] = acc2[n][r] + b2v[n];
            }
        }
    }
}

extern "C" void kernel_launch(void* const* d_in, const int* in_sizes, int n_in,
                              void* d_out, int out_size, void* d_ws, size_t ws_size,
                              hipStream_t stream) {
    const float* feat = (const float*)d_in[0];
    const int* src    = (const int*)d_in[1];
    const int* dst    = (const int*)d_in[2];
    const float* eps  = (const float*)d_in[3];
    const float* W1   = (const float*)d_in[4];
    const float* b1   = (const float*)d_in[5];
    const float* W2   = (const float*)d_in[6];
    const float* b2   = (const float*)d_in[7];
    float* out = (float*)d_out;

    char* ws = (char*)d_ws;
    int*      bincnt  = (int*)ws;                          //   100,352 B (391 x 256B padded)
    int*      rowptr  = (int*)(ws + 100352);               //   401,408 B
    int*      csr     = (int*)(ws + 501760);               // 12,800,000 B
    uint32_t* binpair = (uint32_t*)(ws + 13301760);        // 15,915,264 B (391 x 10176 x 4)
    uint32_t* featp   = (uint32_t*)(ws + 29217024);        // 25,600,000 B (2 pass tables)
    uint32_t* hbf     = (uint32_t*)(ws + 54817024);        // 25,608,192 B
    short*    w1t     = (short*)(ws + 80425216);           //     32,768 B
    short*    w2t     = (short*)(ws + 80457984);           // ends 80,490,752 B

    prep_kernel<<<12662, 256, 0, stream>>>(feat, featp, W1, W2, w1t, w2t, bincnt);
    bin_kernel<<<(N_EDGES + EPB - 1) / EPB, 256, 0, stream>>>(src, dst, bincnt, binpair);
    csr_kernel<<<NBINS, 1024, 0, stream>>>(bincnt, binpair, rowptr, csr);
    gather_kernel<<<NPAD / 4, 256, 0, stream>>>(featp, rowptr, csr, eps, hbf, 0);
    gather_kernel<<<NPAD / 4, 256, 0, stream>>>(featp + PASSU32, rowptr, csr, eps, hbf, 32);
    mlp_kernel<<<256, 512, 0, stream>>>((const short*)hbf, w1t, w2t, b1, b2, out);
}